// Round 4
// baseline (263.322 us; speedup 1.0000x reference)
//
#include <hip/hip_runtime.h>
#include <hip/hip_bf16.h>

// Problem: B=4, N=2048, IN=256, H=8, ATN=32
//   xt = x@W + b            [B,H,N,32]
//   xC = xt @ C^T           [B,H,N,32]
//   S  = xC @ xt^T          [B,H,N,N]
//   alpha = tanh(S * adj)   [B,H,N,N]    (never materialized)
//   heads = alpha @ xt      [B,H,N,32] -> out [B,N,256] fp32
//
// R4: k_attn restructured so tanh output feeds the PV MFMA DIRECTLY in
// registers (no LDS round-trip, no cross-lane):
//   - S-MFMA A-rows fed in permuted order p(a)=8*(a>>2)+(a&3) (+4 for the
//     second MFMA) => lane(c,q) holds S[m0+8q+j][n], j=0..7 — exactly the
//     PV B-operand fragment (PV computed as O^T = xtT * alpha^T).
//   - R3's VGPR_Count=44 proved the compiler SANK the register prefetch;
//     now pinned with sched_barrier(0) + launch_bounds(512,4) (128 VGPR cap).
//   - k_attn uses zero LDS; waves fully independent (no barriers).

typedef __bf16 bf16;
typedef __attribute__((ext_vector_type(8))) __bf16 bf16x8;
typedef __attribute__((ext_vector_type(4))) __bf16 bf16x4;
typedef __attribute__((ext_vector_type(4))) float  f32x4;

#define MFMA(a, b, c) __builtin_amdgcn_mfma_f32_16x16x32_bf16(a, b, c, 0, 0, 0)

// Padé tanh: x(945 + 105 t + t^2)/(945 + 420 t + 15 t^2), t = x^2, clamped.
__device__ __forceinline__ float fast_tanh(float x) {
    float t   = x * x;
    float num = x * __builtin_fmaf(t, t + 105.0f, 945.0f);
    float den = __builtin_fmaf(t, __builtin_fmaf(t, 15.0f, 420.0f), 945.0f);
    float r   = num * __builtin_amdgcn_rcpf(den);
    return __builtin_amdgcn_fmed3f(r, -1.0f, 1.0f);
}

#define BB   4
#define NN   2048
#define IND  256
#define HH   8
#define ATN  32

// workspace layout (bytes)
#define OFF_XBF  0u            // x as bf16 [B][N][IN]      (4 MB)
#define OFF_XT   4194304u      // xt  [B][H][N][32] bf16    (4 MB)
#define OFF_XC   8388608u      // xC  [B][H][N][32] bf16    (4 MB)
#define OFF_XTT  12582912u     // xt^T[B][H][32][N] bf16    (4 MB)
#define OFF_WT   16777216u     // W^T [H][32][256]  bf16    (128 KB)
#define OFF_CB   16908288u     // C   [H][32][32]   bf16    (16 KB)

// ---------------- kernel 0: dtype conversion + out zero ----------------
__global__ __launch_bounds__(256) void k_prep(const float* __restrict__ x,
                                              const float* __restrict__ W,
                                              const float* __restrict__ C,
                                              bf16* __restrict__ xbf,
                                              bf16* __restrict__ WT,
                                              bf16* __restrict__ Cb,
                                              float* __restrict__ out) {
    int tid = blockIdx.x * 256 + threadIdx.x;
    if (tid < 524288) {
        float4 v = ((const float4*)x)[tid];
        bf16x4 o;
        o[0] = (bf16)v.x; o[1] = (bf16)v.y; o[2] = (bf16)v.z; o[3] = (bf16)v.w;
        *(bf16x4*)(xbf + (size_t)tid * 4) = o;
    } else if (tid < 524288 + 65536) {
        int t = tid - 524288;
        int h = t >> 13, r = t & 8191, i = r >> 5, o = r & 31;
        WT[(h * 32 + o) * 256 + i] = (bf16)W[t];
    } else if (tid < 524288 + 65536 + 8192) {
        int t = tid - (524288 + 65536);
        Cb[t] = (bf16)C[t];
    } else if (tid < 598016 + 524288) {
        int t = tid - 598016;          // zero out[2M floats] as float4
        float4 z = {0.f, 0.f, 0.f, 0.f};
        ((float4*)out)[t] = z;
    }
}

// ---------------- kernel A: projection ----------------
// grid 512 = b(4)*h(8)*ntg(16); 256 thr = 4 waves; wave w -> nt = ntg*4+w.
__global__ __launch_bounds__(256) void k_proj(const bf16* __restrict__ xbf,
                                              const bf16* __restrict__ WT,
                                              const bf16* __restrict__ Cb,
                                              const float* __restrict__ bias,
                                              bf16* __restrict__ xt,
                                              bf16* __restrict__ xc,
                                              bf16* __restrict__ xtT) {
    __shared__ bf16 ldsA_all[4][32 * 40];
    __shared__ bf16 ldsB_all[4][32 * 40];
    int bid = blockIdx.x;
    int ntg = bid & 15, h = (bid >> 4) & 7, b = bid >> 7;
    int wave = threadIdx.x >> 6;
    int lane = threadIdx.x & 63;
    int nt = ntg * 4 + wave;
    int n0 = nt * 32;
    int c = lane & 15, q = lane >> 4;
    bf16* ldsA = ldsA_all[wave];
    bf16* ldsB = ldsB_all[wave];

    f32x4 acc[2][2] = {};
    const bf16* xrow0 = xbf + ((size_t)(b * NN + n0 + c) * IND + q * 8);
    const bf16* xrow1 = xbf + ((size_t)(b * NN + n0 + 16 + c) * IND + q * 8);
    const bf16* wrow0 = WT + ((h * 32 + c) * IND + q * 8);
    const bf16* wrow1 = WT + ((h * 32 + 16 + c) * IND + q * 8);
#pragma unroll
    for (int k0 = 0; k0 < IND; k0 += 32) {
        bf16x8 a0 = *(const bf16x8*)(xrow0 + k0);
        bf16x8 a1 = *(const bf16x8*)(xrow1 + k0);
        bf16x8 w0 = *(const bf16x8*)(wrow0 + k0);
        bf16x8 w1 = *(const bf16x8*)(wrow1 + k0);
        acc[0][0] = MFMA(a0, w0, acc[0][0]);
        acc[0][1] = MFMA(a0, w1, acc[0][1]);
        acc[1][0] = MFMA(a1, w0, acc[1][0]);
        acc[1][1] = MFMA(a1, w1, acc[1][1]);
    }
    float bv[2] = { bias[h * 32 + c], bias[h * 32 + 16 + c] };
    size_t bh = (size_t)(b * HH + h);
    // C/D layout: row(n_local) = q*4+r (+16*nq), col(o_local) = c (+16*oq)
#pragma unroll
    for (int nq = 0; nq < 2; ++nq)
#pragma unroll
        for (int oq = 0; oq < 2; ++oq)
#pragma unroll
            for (int r = 0; r < 4; ++r)
                ldsA[(nq * 16 + q * 4 + r) * 40 + oq * 16 + c] =
                    (bf16)(acc[nq][oq][r] + bv[oq]);
    // xC = xt @ C^T : B[k=o][col=p] = C[p][o] (row-major C)
    f32x4 acc2[2][2] = {};
    bf16x8 aL0 = *(const bf16x8*)(ldsA + (c) * 40 + q * 8);
    bf16x8 aL1 = *(const bf16x8*)(ldsA + (16 + c) * 40 + q * 8);
    bf16x8 c0 = *(const bf16x8*)(Cb + h * 1024 + (c) * 32 + q * 8);
    bf16x8 c1 = *(const bf16x8*)(Cb + h * 1024 + (16 + c) * 32 + q * 8);
    acc2[0][0] = MFMA(aL0, c0, acc2[0][0]);
    acc2[0][1] = MFMA(aL0, c1, acc2[0][1]);
    acc2[1][0] = MFMA(aL1, c0, acc2[1][0]);
    acc2[1][1] = MFMA(aL1, c1, acc2[1][1]);
#pragma unroll
    for (int nq = 0; nq < 2; ++nq)
#pragma unroll
        for (int pq = 0; pq < 2; ++pq)
#pragma unroll
            for (int r = 0; r < 4; ++r)
                ldsB[(nq * 16 + q * 4 + r) * 40 + pq * 16 + c] =
                    (bf16)acc2[nq][pq][r];

    // ---- coalesced stores from LDS (per-wave, no cross-wave deps) ----
    {
        int n = lane >> 1, half = lane & 1;
        bf16x8 t0 = *(const bf16x8*)(ldsA + n * 40 + half * 16);
        bf16x8 t1 = *(const bf16x8*)(ldsA + n * 40 + half * 16 + 8);
        bf16* dst = xt + (bh * NN + n0 + n) * ATN + half * 16;
        *(bf16x8*)(dst) = t0;
        *(bf16x8*)(dst + 8) = t1;
        bf16x8 u0 = *(const bf16x8*)(ldsB + n * 40 + half * 16);
        bf16x8 u1 = *(const bf16x8*)(ldsB + n * 40 + half * 16 + 8);
        bf16* dst2 = xc + (bh * NN + n0 + n) * ATN + half * 16;
        *(bf16x8*)(dst2) = u0;
        *(bf16x8*)(dst2 + 8) = u1;
    }
    {
        int o = lane >> 1, nh = lane & 1;
        bf16x8 t0, t1;
#pragma unroll
        for (int i = 0; i < 8; ++i) {
            t0[i] = ldsA[(nh * 16 + i) * 40 + o];
            t1[i] = ldsA[(nh * 16 + 8 + i) * 40 + o];
        }
        bf16* dst = xtT + (bh * ATN + o) * NN + n0 + nh * 16;
        *(bf16x8*)(dst) = t0;
        *(bf16x8*)(dst + 8) = t1;
    }
}

// ---------------- kernel B: fused scores/tanh/PV, all-register ----------------
// grid 1024 = chunk(4) * b(4) * ntile(64); 512 thr = 8 waves; wave == head.
// S-MFMA with permuted A rows => S lands in PV's B-operand layout; tanh is
// applied in-register; PV computes O^T = xtT * alpha^T. Zero LDS, no
// barriers, register double-buffered prefetch pinned by sched_barrier(0).
__global__ __launch_bounds__(512, 4) void k_attn(const float* __restrict__ adj,
                                                 const bf16* __restrict__ xt,
                                                 const bf16* __restrict__ xc,
                                                 const bf16* __restrict__ xtT,
                                                 float* __restrict__ out) {
    int bid = blockIdx.x;
    int chunk = bid >> 8;
    int bn = bid & 255;
    int nt = bn & 63, b = bn >> 6;
    int n0 = nt * 32;
    int wave = threadIdx.x >> 6;            // == head
    int lane = threadIdx.x & 63;
    int c = lane & 15, q = lane >> 4;
    int p = 8 * (c >> 2) + (c & 3);         // A-row permutation
    size_t bh = (size_t)(b * HH + wave);
    const bf16* xt_h = xt + bh * NN * ATN;
    const bf16* xc_h = xc + bh * NN * ATN;
    const bf16* xtT_h = xtT + bh * ATN * NN;
    const float* adj_b = adj + (size_t)b * NN * NN;

    // scores B-operand (persistent): B[k=o][col=n] = xC[n0+n][o]
    bf16x8 bXC0 = *(const bf16x8*)(xc_h + (n0 + c) * ATN + q * 8);
    bf16x8 bXC1 = *(const bf16x8*)(xc_h + (n0 + 16 + c) * ATN + q * 8);
    f32x4 accO[2][2] = {};                  // O^T [oq][nq]
    const f32x4 z = {0.f, 0.f, 0.f, 0.f};

    const int m_beg = chunk * 512;

    // double-buffered per-tile inputs (~32 VGPR per buffer)
    bf16x8 aXT[2][2];   // S A-frags: xt rows m0+p (half 0) and m0+p+4 (half 1)
    bf16x8 aO[2][2];    // PV A-frags: xtT[o][m], oq = 0,1
    f32x4  adjv[2][4];  // adj[n][m]: [nq*2 + jhalf]

#define LOAD_TILE(buf, m0) do {                                                          \
        aXT[buf][0] = *(const bf16x8*)(xt_h + (size_t)((m0) + p) * ATN + q * 8);         \
        aXT[buf][1] = *(const bf16x8*)(xt_h + (size_t)((m0) + p + 4) * ATN + q * 8);     \
        aO[buf][0]  = *(const bf16x8*)(xtT_h + (size_t)(c) * NN + (m0) + q * 8);         \
        aO[buf][1]  = *(const bf16x8*)(xtT_h + (size_t)(16 + c) * NN + (m0) + q * 8);    \
        adjv[buf][0] = *(const f32x4*)(adj_b + (size_t)(n0 + c) * NN + (m0) + q * 8);    \
        adjv[buf][1] = *(const f32x4*)(adj_b + (size_t)(n0 + c) * NN + (m0) + q * 8 + 4);\
        adjv[buf][2] = *(const f32x4*)(adj_b + (size_t)(n0 + 16 + c) * NN + (m0) + q * 8);    \
        adjv[buf][3] = *(const f32x4*)(adj_b + (size_t)(n0 + 16 + c) * NN + (m0) + q * 8 + 4);\
    } while (0)

    LOAD_TILE(0, m_beg);
#pragma unroll
    for (int i = 0; i < 16; ++i) {
        const int cur = i & 1, nxt = cur ^ 1;
        const int m0 = m_beg + i * 32;
        if (i < 15) LOAD_TILE(nxt, m0 + 32);        // prefetch next tile
        __builtin_amdgcn_sched_barrier(0);          // pin loads above compute

        // S[m0+8q+j][n]: half a -> j=r, half b -> j=4+r (A-row permutation)
        f32x4 S0a = MFMA(aXT[cur][0], bXC0, z);     // n = n0+c
        f32x4 S0b = MFMA(aXT[cur][1], bXC0, z);
        f32x4 S1a = MFMA(aXT[cur][0], bXC1, z);     // n = n0+16+c
        f32x4 S1b = MFMA(aXT[cur][1], bXC1, z);

        bf16x8 P0, P1;   // PV B-frags: B[k=8q+j][col=c(+16)] = alpha[n][m0+8q+j]
#pragma unroll
        for (int r = 0; r < 4; ++r) {
            P0[r]     = (bf16)fast_tanh(S0a[r] * adjv[cur][0][r]);
            P0[4 + r] = (bf16)fast_tanh(S0b[r] * adjv[cur][1][r]);
            P1[r]     = (bf16)fast_tanh(S1a[r] * adjv[cur][2][r]);
            P1[4 + r] = (bf16)fast_tanh(S1b[r] * adjv[cur][3][r]);
        }
        // O^T[o][n] += xtT[o][m] * alpha^T[m][n]
        accO[0][0] = MFMA(aO[cur][0], P0, accO[0][0]);
        accO[0][1] = MFMA(aO[cur][0], P1, accO[0][1]);
        accO[1][0] = MFMA(aO[cur][1], P0, accO[1][0]);
        accO[1][1] = MFMA(aO[cur][1], P1, accO[1][1]);
    }
#undef LOAD_TILE

    // epilogue: O^T D-layout: o = oq*16 + 4q + r, n = n0 + nq*16 + c
#pragma unroll
    for (int oq = 0; oq < 2; ++oq)
#pragma unroll
        for (int nq = 0; nq < 2; ++nq)
#pragma unroll
            for (int r = 0; r < 4; ++r) {
                int n = n0 + nq * 16 + c;
                int o = wave * 32 + oq * 16 + 4 * q + r;
                unsafeAtomicAdd(&out[((size_t)b * NN + n) * (HH * ATN) + o],
                                accO[oq][nq][r]);
            }
}

extern "C" void kernel_launch(void* const* d_in, const int* in_sizes, int n_in,
                              void* d_out, int out_size, void* d_ws, size_t ws_size,
                              hipStream_t stream) {
    const float* x    = (const float*)d_in[0];   // [4,2048,256]
    const float* adj  = (const float*)d_in[1];   // [4,2048,2048]
    const float* W    = (const float*)d_in[2];   // [8,256,32]
    const float* bias = (const float*)d_in[3];   // [8,32]
    const float* C    = (const float*)d_in[4];   // [8,32,32]
    float* out = (float*)d_out;                  // [4,2048,256]

    char* ws = (char*)d_ws;                      // ~16.9 MB
    bf16* xbf = (bf16*)(ws + OFF_XBF);
    bf16* xt  = (bf16*)(ws + OFF_XT);
    bf16* xc  = (bf16*)(ws + OFF_XC);
    bf16* xtT = (bf16*)(ws + OFF_XTT);
    bf16* WT  = (bf16*)(ws + OFF_WT);
    bf16* Cb  = (bf16*)(ws + OFF_CB);

    k_prep<<<4384, 256, 0, stream>>>(x, W, C, xbf, WT, Cb, out);
    k_proj<<<512, 256, 0, stream>>>(xbf, WT, Cb, bias, xt, xc, xtT);
    k_attn<<<1024, 512, 0, stream>>>(adj, xt, xc, xtT, out);
}

// Round 5
// 178.673 us; speedup vs baseline: 1.4738x; 1.4738x over previous
//
#include <hip/hip_runtime.h>
#include <hip/hip_bf16.h>

// Problem: B=4, N=2048, IN=256, H=8, ATN=32
//   xt = x@W + b            [B,H,N,32]
//   xC = xt @ C^T           [B,H,N,32]
//   S  = xC @ xt^T          [B,H,N,N]
//   alpha = tanh(S * adj)   [B,H,N,N]    (never materialized)
//   heads = alpha @ xt      [B,H,N,32] -> out [B,N,256] fp32
//
// R5: the compiler defeated register prefetch twice (R3 VGPR=44, R4 VGPR=64
// — allocator sinks loads to uses). Switch to the one mechanism it cannot
// defeat: global_load_lds (zero VGPR cost, vmcnt-tracked DMA).
//   - adj tiles DMA'd to LDS depth-2 ahead, 4 buffers, SHARED by all 8
//     waves (adj is head-invariant! cuts adj L2 traffic 8x). XOR-swizzled
//     DMA source addresses => conflict-free ds_read_b128 consumption.
//   - raw s_barrier + hand-counted s_waitcnt vmcnt(6/5/0) (no __syncthreads
//     drain), sched_barrier(0) fences around the barrier.
//   - xt/xtT frags: depth-1 register prefetch (32 VGPR, now fits).
//   - atomics removed: chunk1 -> out, chunk0 -> slab, k_reduce adds.

typedef __bf16 bf16;
typedef __attribute__((ext_vector_type(8))) __bf16 bf16x8;
typedef __attribute__((ext_vector_type(4))) __bf16 bf16x4;
typedef __attribute__((ext_vector_type(4))) float  f32x4;

#define MFMA(a, b, c) __builtin_amdgcn_mfma_f32_16x16x32_bf16(a, b, c, 0, 0, 0)

// async global->LDS DMA, 16 B/lane; LDS dest = wave-uniform base + lane*16
#define GLDS16(g, l) __builtin_amdgcn_global_load_lds(                        \
        (const __attribute__((address_space(1))) void*)(g),                   \
        (__attribute__((address_space(3))) void*)(l), 16, 0, 0)

// s_waitcnt imm: vmcnt[3:0] | expcnt(7)<<4 | lgkmcnt(15)<<8 | vmcnt[5:4]<<14
#define WAITVM6() __builtin_amdgcn_s_waitcnt(0x0F76)
#define WAITVM5() __builtin_amdgcn_s_waitcnt(0x0F75)
#define WAITVM0() __builtin_amdgcn_s_waitcnt(0x0F70)
#define FENCE()   __builtin_amdgcn_sched_barrier(0)
#define BAR()     __builtin_amdgcn_s_barrier()

// Padé tanh: x(945 + 105 t + t^2)/(945 + 420 t + 15 t^2), t = x^2, clamped.
__device__ __forceinline__ float fast_tanh(float x) {
    float t   = x * x;
    float num = x * __builtin_fmaf(t, t + 105.0f, 945.0f);
    float den = __builtin_fmaf(t, __builtin_fmaf(t, 15.0f, 420.0f), 945.0f);
    float r   = num * __builtin_amdgcn_rcpf(den);
    return __builtin_amdgcn_fmed3f(r, -1.0f, 1.0f);
}

#define BB   4
#define NN   2048
#define IND  256
#define HH   8
#define ATN  32

// workspace layout (bytes)
#define OFF_XBF   0u           // x as bf16 [B][N][IN]      (4 MB)
#define OFF_XT    4194304u     // xt  [B][H][N][32] bf16    (4 MB)
#define OFF_XC    8388608u     // xC  [B][H][N][32] bf16    (4 MB)
#define OFF_XTT   12582912u    // xt^T[B][H][32][N] bf16    (4 MB)
#define OFF_WT    16777216u    // W^T [H][32][256]  bf16    (128 KB)
#define OFF_CB    16908288u    // C   [H][32][32]   bf16    (16 KB)
#define OFF_SLAB  16924672u    // chunk-0 partial out, fp32 (8 MB) -> ~25.3 MB

// ---------------- kernel 0: dtype conversion ----------------
__global__ __launch_bounds__(256) void k_prep(const float* __restrict__ x,
                                              const float* __restrict__ W,
                                              const float* __restrict__ C,
                                              bf16* __restrict__ xbf,
                                              bf16* __restrict__ WT,
                                              bf16* __restrict__ Cb) {
    int tid = blockIdx.x * 256 + threadIdx.x;
    if (tid < 524288) {
        float4 v = ((const float4*)x)[tid];
        bf16x4 o;
        o[0] = (bf16)v.x; o[1] = (bf16)v.y; o[2] = (bf16)v.z; o[3] = (bf16)v.w;
        *(bf16x4*)(xbf + (size_t)tid * 4) = o;
    } else if (tid < 524288 + 65536) {
        int t = tid - 524288;
        int h = t >> 13, r = t & 8191, i = r >> 5, o = r & 31;
        WT[(h * 32 + o) * 256 + i] = (bf16)W[t];
    } else if (tid < 524288 + 65536 + 8192) {
        int t = tid - (524288 + 65536);
        Cb[t] = (bf16)C[t];
    }
}

// ---------------- kernel A: projection ----------------
// grid 512 = b(4)*h(8)*ntg(16); 256 thr = 4 waves; wave w -> nt = ntg*4+w.
__global__ __launch_bounds__(256) void k_proj(const bf16* __restrict__ xbf,
                                              const bf16* __restrict__ WT,
                                              const bf16* __restrict__ Cb,
                                              const float* __restrict__ bias,
                                              bf16* __restrict__ xt,
                                              bf16* __restrict__ xc,
                                              bf16* __restrict__ xtT) {
    __shared__ bf16 ldsA_all[4][32 * 40];
    __shared__ bf16 ldsB_all[4][32 * 40];
    int bid = blockIdx.x;
    int ntg = bid & 15, h = (bid >> 4) & 7, b = bid >> 7;
    int wave = threadIdx.x >> 6;
    int lane = threadIdx.x & 63;
    int nt = ntg * 4 + wave;
    int n0 = nt * 32;
    int c = lane & 15, q = lane >> 4;
    bf16* ldsA = ldsA_all[wave];
    bf16* ldsB = ldsB_all[wave];

    f32x4 acc[2][2] = {};
    const bf16* xrow0 = xbf + ((size_t)(b * NN + n0 + c) * IND + q * 8);
    const bf16* xrow1 = xbf + ((size_t)(b * NN + n0 + 16 + c) * IND + q * 8);
    const bf16* wrow0 = WT + ((h * 32 + c) * IND + q * 8);
    const bf16* wrow1 = WT + ((h * 32 + 16 + c) * IND + q * 8);
#pragma unroll
    for (int k0 = 0; k0 < IND; k0 += 32) {
        bf16x8 a0 = *(const bf16x8*)(xrow0 + k0);
        bf16x8 a1 = *(const bf16x8*)(xrow1 + k0);
        bf16x8 w0 = *(const bf16x8*)(wrow0 + k0);
        bf16x8 w1 = *(const bf16x8*)(wrow1 + k0);
        acc[0][0] = MFMA(a0, w0, acc[0][0]);
        acc[0][1] = MFMA(a0, w1, acc[0][1]);
        acc[1][0] = MFMA(a1, w0, acc[1][0]);
        acc[1][1] = MFMA(a1, w1, acc[1][1]);
    }
    float bv[2] = { bias[h * 32 + c], bias[h * 32 + 16 + c] };
    size_t bh = (size_t)(b * HH + h);
#pragma unroll
    for (int nq = 0; nq < 2; ++nq)
#pragma unroll
        for (int oq = 0; oq < 2; ++oq)
#pragma unroll
            for (int r = 0; r < 4; ++r)
                ldsA[(nq * 16 + q * 4 + r) * 40 + oq * 16 + c] =
                    (bf16)(acc[nq][oq][r] + bv[oq]);
    f32x4 acc2[2][2] = {};
    bf16x8 aL0 = *(const bf16x8*)(ldsA + (c) * 40 + q * 8);
    bf16x8 aL1 = *(const bf16x8*)(ldsA + (16 + c) * 40 + q * 8);
    bf16x8 c0 = *(const bf16x8*)(Cb + h * 1024 + (c) * 32 + q * 8);
    bf16x8 c1 = *(const bf16x8*)(Cb + h * 1024 + (16 + c) * 32 + q * 8);
    acc2[0][0] = MFMA(aL0, c0, acc2[0][0]);
    acc2[0][1] = MFMA(aL0, c1, acc2[0][1]);
    acc2[1][0] = MFMA(aL1, c0, acc2[1][0]);
    acc2[1][1] = MFMA(aL1, c1, acc2[1][1]);
#pragma unroll
    for (int nq = 0; nq < 2; ++nq)
#pragma unroll
        for (int pq = 0; pq < 2; ++pq)
#pragma unroll
            for (int r = 0; r < 4; ++r)
                ldsB[(nq * 16 + q * 4 + r) * 40 + pq * 16 + c] =
                    (bf16)acc2[nq][pq][r];

    {   // coalesced xt/xc stores
        int n = lane >> 1, half = lane & 1;
        bf16x8 t0 = *(const bf16x8*)(ldsA + n * 40 + half * 16);
        bf16x8 t1 = *(const bf16x8*)(ldsA + n * 40 + half * 16 + 8);
        bf16* dst = xt + (bh * NN + n0 + n) * ATN + half * 16;
        *(bf16x8*)(dst) = t0;
        *(bf16x8*)(dst + 8) = t1;
        bf16x8 u0 = *(const bf16x8*)(ldsB + n * 40 + half * 16);
        bf16x8 u1 = *(const bf16x8*)(ldsB + n * 40 + half * 16 + 8);
        bf16* dst2 = xc + (bh * NN + n0 + n) * ATN + half * 16;
        *(bf16x8*)(dst2) = u0;
        *(bf16x8*)(dst2 + 8) = u1;
    }
    {   // xtT via LDS-gathered transpose
        int o = lane >> 1, nh = lane & 1;
        bf16x8 t0, t1;
#pragma unroll
        for (int i = 0; i < 8; ++i) {
            t0[i] = ldsA[(nh * 16 + i) * 40 + o];
            t1[i] = ldsA[(nh * 16 + 8 + i) * 40 + o];
        }
        bf16* dst = xtT + (bh * ATN + o) * NN + n0 + nh * 16;
        *(bf16x8*)(dst) = t0;
        *(bf16x8*)(dst + 8) = t1;
    }
}

// ---------------- kernel B: fused scores/tanh/PV, DMA-pipelined ----------------
// grid 512 = chunk(2) * b(4) * ntile(64); 512 thr = 8 waves; wave == head.
// Per m-tile (32): adj tile (4 KB fp32) arrives via global_load_lds issued
// 2 tiles ahead by waves 0-3 (1/4 tile each, XOR-swizzled source so the
// ds_read_b128 consumption is 2-way i.e. conflict-free). Raw s_barrier +
// exact vmcnt counts keep the queue full across iterations.
__global__ __launch_bounds__(512, 4) void k_attn(const float* __restrict__ adj,
                                                 const bf16* __restrict__ xt,
                                                 const bf16* __restrict__ xc,
                                                 const bf16* __restrict__ xtT,
                                                 float* __restrict__ slab,
                                                 float* __restrict__ out) {
    __shared__ float adjlds[4 * 1024];      // 4 buffers x 32n x 32m fp32 (16 KB)
    int bid = blockIdx.x;
    int chunk = bid >> 8;
    int bn = bid & 255;
    int nt = bn & 63, b = bn >> 6;
    int n0 = nt * 32;
    int wave = threadIdx.x >> 6;            // == head
    int lane = threadIdx.x & 63;
    int c = lane & 15, q = lane >> 4;
    int p = 8 * (c >> 2) + (c & 3);         // S A-row permutation
    size_t bh = (size_t)(b * HH + wave);
    const bf16* xt_h = xt + bh * NN * ATN;
    const bf16* xc_h = xc + bh * NN * ATN;
    const bf16* xtT_h = xtT + bh * ATN * NN;
    const float* adj_b = adj + (size_t)b * NN * NN;
    const int m_beg = chunk * 1024;         // 32 tiles of 32

    // DMA source (waves 0-3): lane L covers LDS 16B-block Bk = wave*64+L;
    // n = Bk>>3, sub' = Bk&7, global sub = sub' ^ (n&7)  (XOR swizzle)
    int nloc = wave * 8 + (lane >> 3);
    int gsub = (lane & 7) ^ (lane >> 3);
    const float* gA = adj_b + (size_t)(n0 + nloc) * NN + gsub * 4 + m_beg;

#define DMA(t) do { if (wave < 4)                                              \
        GLDS16(gA + (t) * 32, adjlds + ((t) & 3) * 1024 + wave * 256);         \
    } while (0)

    // persistent S B-operand: B[k=o][col=n] = xC[n0+n][o]
    bf16x8 bXC0 = *(const bf16x8*)(xc_h + (n0 + c) * ATN + q * 8);
    bf16x8 bXC1 = *(const bf16x8*)(xc_h + (n0 + 16 + c) * ATN + q * 8);
    f32x4 accO[2][2] = {};                  // O^T [oq][nq]
    const f32x4 z = {0.f, 0.f, 0.f, 0.f};

    // depth-1 register prefetch, explicit even/odd buffers
    bf16x8 xA0e, xA1e, oA0e, oA1e, xA0o, xA1o, oA0o, oA1o;
#define REGS_E(t) do { int m0 = m_beg + (t) * 32;                              \
        xA0e = *(const bf16x8*)(xt_h + (size_t)(m0 + p) * ATN + q * 8);        \
        xA1e = *(const bf16x8*)(xt_h + (size_t)(m0 + p + 4) * ATN + q * 8);    \
        oA0e = *(const bf16x8*)(xtT_h + (size_t)(c) * NN + m0 + q * 8);        \
        oA1e = *(const bf16x8*)(xtT_h + (size_t)(16 + c) * NN + m0 + q * 8);   \
    } while (0)
#define REGS_O(t) do { int m0 = m_beg + (t) * 32;                              \
        xA0o = *(const bf16x8*)(xt_h + (size_t)(m0 + p) * ATN + q * 8);        \
        xA1o = *(const bf16x8*)(xt_h + (size_t)(m0 + p + 4) * ATN + q * 8);    \
        oA0o = *(const bf16x8*)(xtT_h + (size_t)(c) * NN + m0 + q * 8);        \
        oA1o = *(const bf16x8*)(xtT_h + (size_t)(16 + c) * NN + m0 + q * 8);   \
    } while (0)

    // lane reads adj[n0+c(+16)][m0+8q..8q+7] from swizzled LDS tile
    int ad00 = c * 32 + ((2 * q) ^ (c & 7)) * 4;
    int ad01 = c * 32 + ((2 * q + 1) ^ (c & 7)) * 4;
    int ad10 = (16 + c) * 32 + ((2 * q) ^ (c & 7)) * 4;
    int ad11 = (16 + c) * 32 + ((2 * q + 1) ^ (c & 7)) * 4;

#define COMPUTE(t, xA0, xA1, oA0, oA1) do {                                    \
        const float* lb = adjlds + ((t) & 3) * 1024;                           \
        f32x4 A00 = *(const f32x4*)(lb + ad00);                                \
        f32x4 A01 = *(const f32x4*)(lb + ad01);                                \
        f32x4 A10 = *(const f32x4*)(lb + ad10);                                \
        f32x4 A11 = *(const f32x4*)(lb + ad11);                                \
        f32x4 S0a = MFMA(xA0, bXC0, z);     /* S[m0+8q+r  ][n0+c]    */        \
        f32x4 S0b = MFMA(xA1, bXC0, z);     /* S[m0+8q+4+r][n0+c]    */        \
        f32x4 S1a = MFMA(xA0, bXC1, z);     /* S[m0+8q+r  ][n0+16+c] */        \
        f32x4 S1b = MFMA(xA1, bXC1, z);                                        \
        bf16x8 P0, P1;                                                         \
        _Pragma("unroll") for (int r = 0; r < 4; ++r) {                        \
            P0[r]     = (bf16)fast_tanh(S0a[r] * A00[r]);                      \
            P0[4 + r] = (bf16)fast_tanh(S0b[r] * A01[r]);                      \
            P1[r]     = (bf16)fast_tanh(S1a[r] * A10[r]);                      \
            P1[4 + r] = (bf16)fast_tanh(S1b[r] * A11[r]);                      \
        }                                                                      \
        accO[0][0] = MFMA(oA0, P0, accO[0][0]);                                \
        accO[0][1] = MFMA(oA0, P1, accO[0][1]);                                \
        accO[1][0] = MFMA(oA1, P0, accO[1][0]);                                \
        accO[1][1] = MFMA(oA1, P1, accO[1][1]);                                \
    } while (0)

    // ---- pipeline: DMA depth 2, regs depth 1 ----
    REGS_E(0);
    DMA(0);
    DMA(1);
    for (int tt = 0; tt < 30; tt += 2) {
        DMA(tt + 2);
        REGS_O(tt + 1);
        FENCE(); WAITVM6(); BAR(); FENCE();     // younger: DMA(t+1,t+2)+regs(t+1)x4 = 6
        COMPUTE(tt, xA0e, xA1e, oA0e, oA1e);
        DMA(tt + 3);
        REGS_E(tt + 2);
        FENCE(); WAITVM6(); BAR(); FENCE();
        COMPUTE(tt + 1, xA0o, xA1o, oA0o, oA1o);
    }
    // t=30: younger = DMA(31) + regs(31)x4 = 5
    REGS_O(31);
    FENCE(); WAITVM5(); BAR(); FENCE();
    COMPUTE(30, xA0e, xA1e, oA0e, oA1e);
    // t=31: nothing younger
    FENCE(); WAITVM0(); BAR(); FENCE();
    COMPUTE(31, xA0o, xA1o, oA0o, oA1o);

#undef DMA
#undef REGS_E
#undef REGS_O
#undef COMPUTE

    // epilogue: O^T: o = wave*32 + oq*16 + 4q + r, n = n0 + nq*16 + c.
    // chunk 1 -> out, chunk 0 -> slab; k_reduce adds them. Plain stores.
    float* dst = (chunk == 0) ? slab : out;
#pragma unroll
    for (int oq = 0; oq < 2; ++oq)
#pragma unroll
        for (int nq = 0; nq < 2; ++nq) {
            size_t n = n0 + nq * 16 + c;
            *(f32x4*)&dst[((size_t)b * NN + n) * 256 + wave * 32 + oq * 16 + 4 * q] =
                accO[oq][nq];
        }
}

// ---------------- kernel C: out += slab ----------------
__global__ __launch_bounds__(256) void k_reduce(const float* __restrict__ slab,
                                                float* __restrict__ out) {
    int i = blockIdx.x * 256 + threadIdx.x;   // f32x4 index, 524288 total
    f32x4 a = ((const f32x4*)out)[i];
    f32x4 s = ((const f32x4*)slab)[i];
    ((f32x4*)out)[i] = a + s;
}

extern "C" void kernel_launch(void* const* d_in, const int* in_sizes, int n_in,
                              void* d_out, int out_size, void* d_ws, size_t ws_size,
                              hipStream_t stream) {
    const float* x    = (const float*)d_in[0];   // [4,2048,256]
    const float* adj  = (const float*)d_in[1];   // [4,2048,2048]
    const float* W    = (const float*)d_in[2];   // [8,256,32]
    const float* bias = (const float*)d_in[3];   // [8,32]
    const float* C    = (const float*)d_in[4];   // [8,32,32]
    float* out = (float*)d_out;                  // [4,2048,256]

    char* ws = (char*)d_ws;                      // ~25.3 MB
    bf16*  xbf  = (bf16*)(ws + OFF_XBF);
    bf16*  xt   = (bf16*)(ws + OFF_XT);
    bf16*  xc   = (bf16*)(ws + OFF_XC);
    bf16*  xtT  = (bf16*)(ws + OFF_XTT);
    bf16*  WT   = (bf16*)(ws + OFF_WT);
    bf16*  Cb   = (bf16*)(ws + OFF_CB);
    float* slab = (float*)(ws + OFF_SLAB);

    k_prep<<<2336, 256, 0, stream>>>(x, W, C, xbf, WT, Cb);
    k_proj<<<512, 256, 0, stream>>>(xbf, WT, Cb, bias, xt, xc, xtT);
    k_attn<<<512, 512, 0, stream>>>(adj, xt, xc, xtT, slab, out);
    k_reduce<<<2048, 256, 0, stream>>>(slab, out);
}

// Round 8
// 175.301 us; speedup vs baseline: 1.5021x; 1.0192x over previous
//
#include <hip/hip_runtime.h>
#include <hip/hip_bf16.h>

// Problem: B=4, N=2048, IN=256, H=8, ATN=32
//   xt = x@W + b; xC = xt@C^T; S = xC@xt^T; alpha = tanh(S*adj);
//   out = concat_h(alpha @ xt)  [B,N,256] fp32
//
// R8: R6/R7 isolation proved the packed-tanh INLINE ASM was the corruption
// source (same failure signature with two different pipelines; R5 pipeline
// passed with scalar tanh). Inline VOP3P asm manages no VALU/trans/MFMA
// hazards -> discarded. This round = exact R5 k_attn body (scalar Padé
// tanh, DMA depth 2, vmcnt(6/5/0), mask-0 fences) with ONE change driven
// by R5's counters (VALUBusy 60%, Occupancy 30% = 2 blocks/CU):
//   chunks 2 -> 4: grid 1024 = 4 blocks/CU = 32 waves/CU, so co-resident
//   blocks fill each other's barrier-drain gaps. Partials for chunks 0-2
//   go to bf16 slabs (slab0 reuses dead xbf region -> ws stays 25.3 MB,
//   bf16 partial rounding adds ~0.3 to absmax vs 24 budget); chunk 3
//   plain-stores f32 to out; k_reduce sums.

typedef __bf16 bf16;
typedef __attribute__((ext_vector_type(8))) __bf16 bf16x8;
typedef __attribute__((ext_vector_type(4))) __bf16 bf16x4;
typedef __attribute__((ext_vector_type(4))) float  f32x4;

#define MFMA(a, b, c) __builtin_amdgcn_mfma_f32_16x16x32_bf16(a, b, c, 0, 0, 0)

// async global->LDS DMA, 16 B/lane; LDS dest = wave-uniform base + lane*16
#define GLDS16(g, l) __builtin_amdgcn_global_load_lds(                        \
        (const __attribute__((address_space(1))) void*)(g),                   \
        (__attribute__((address_space(3))) void*)(l), 16, 0, 0)

// s_waitcnt imm: vmcnt[3:0] | expcnt(7)<<4 | lgkmcnt(15)<<8 | vmcnt[5:4]<<14
#define WAITVM6() __builtin_amdgcn_s_waitcnt(0x0F76)
#define WAITVM5() __builtin_amdgcn_s_waitcnt(0x0F75)
#define WAITVM0() __builtin_amdgcn_s_waitcnt(0x0F70)
#define FENCE()   __builtin_amdgcn_sched_barrier(0)   // R5-proven: nothing crosses
#define BAR()     __builtin_amdgcn_s_barrier()

// Padé tanh (R5-proven scalar form): x(945+105t+t^2)/(945+420t+15t^2), clamped.
__device__ __forceinline__ float fast_tanh(float x) {
    float t   = x * x;
    float num = x * __builtin_fmaf(t, t + 105.0f, 945.0f);
    float den = __builtin_fmaf(t, __builtin_fmaf(t, 15.0f, 420.0f), 945.0f);
    float r   = num * __builtin_amdgcn_rcpf(den);
    return __builtin_amdgcn_fmed3f(r, -1.0f, 1.0f);
}

#define BB   4
#define NN   2048
#define IND  256
#define HH   8
#define ATN  32

// workspace layout (bytes) — total 25.3 MB (same proven footprint as R5)
#define OFF_XBF   0u           // x bf16 (4 MB); DEAD after k_proj -> reused as slab0
#define OFF_XT    4194304u
#define OFF_XC    8388608u
#define OFF_XTT   12582912u
#define OFF_WT    16777216u
#define OFF_CB    16908288u
#define OFF_SLAB  16924672u    // slab1 (4 MB bf16) + slab2 (4 MB bf16)

// ---------------- kernel 0: dtype conversion ----------------
__global__ __launch_bounds__(256) void k_prep(const float* __restrict__ x,
                                              const float* __restrict__ W,
                                              const float* __restrict__ C,
                                              bf16* __restrict__ xbf,
                                              bf16* __restrict__ WT,
                                              bf16* __restrict__ Cb) {
    int tid = blockIdx.x * 256 + threadIdx.x;
    if (tid < 524288) {
        float4 v = ((const float4*)x)[tid];
        bf16x4 o;
        o[0] = (bf16)v.x; o[1] = (bf16)v.y; o[2] = (bf16)v.z; o[3] = (bf16)v.w;
        *(bf16x4*)(xbf + (size_t)tid * 4) = o;
    } else if (tid < 524288 + 65536) {
        int t = tid - 524288;
        int h = t >> 13, r = t & 8191, i = r >> 5, o = r & 31;
        WT[(h * 32 + o) * 256 + i] = (bf16)W[t];
    } else if (tid < 524288 + 65536 + 8192) {
        int t = tid - (524288 + 65536);
        Cb[t] = (bf16)C[t];
    }
}

// ---------------- kernel A: projection ----------------
__global__ __launch_bounds__(256) void k_proj(const bf16* __restrict__ xbf,
                                              const bf16* __restrict__ WT,
                                              const bf16* __restrict__ Cb,
                                              const float* __restrict__ bias,
                                              bf16* __restrict__ xt,
                                              bf16* __restrict__ xc,
                                              bf16* __restrict__ xtT) {
    __shared__ bf16 ldsA_all[4][32 * 40];
    __shared__ bf16 ldsB_all[4][32 * 40];
    int bid = blockIdx.x;
    int ntg = bid & 15, h = (bid >> 4) & 7, b = bid >> 7;
    int wave = threadIdx.x >> 6;
    int lane = threadIdx.x & 63;
    int nt = ntg * 4 + wave;
    int n0 = nt * 32;
    int c = lane & 15, q = lane >> 4;
    bf16* ldsA = ldsA_all[wave];
    bf16* ldsB = ldsB_all[wave];

    f32x4 acc[2][2] = {};
    const bf16* xrow0 = xbf + ((size_t)(b * NN + n0 + c) * IND + q * 8);
    const bf16* xrow1 = xbf + ((size_t)(b * NN + n0 + 16 + c) * IND + q * 8);
    const bf16* wrow0 = WT + ((h * 32 + c) * IND + q * 8);
    const bf16* wrow1 = WT + ((h * 32 + 16 + c) * IND + q * 8);
#pragma unroll
    for (int k0 = 0; k0 < IND; k0 += 32) {
        bf16x8 a0 = *(const bf16x8*)(xrow0 + k0);
        bf16x8 a1 = *(const bf16x8*)(xrow1 + k0);
        bf16x8 w0 = *(const bf16x8*)(wrow0 + k0);
        bf16x8 w1 = *(const bf16x8*)(wrow1 + k0);
        acc[0][0] = MFMA(a0, w0, acc[0][0]);
        acc[0][1] = MFMA(a0, w1, acc[0][1]);
        acc[1][0] = MFMA(a1, w0, acc[1][0]);
        acc[1][1] = MFMA(a1, w1, acc[1][1]);
    }
    float bv[2] = { bias[h * 32 + c], bias[h * 32 + 16 + c] };
    size_t bh = (size_t)(b * HH + h);
#pragma unroll
    for (int nq = 0; nq < 2; ++nq)
#pragma unroll
        for (int oq = 0; oq < 2; ++oq)
#pragma unroll
            for (int r = 0; r < 4; ++r)
                ldsA[(nq * 16 + q * 4 + r) * 40 + oq * 16 + c] =
                    (bf16)(acc[nq][oq][r] + bv[oq]);
    f32x4 acc2[2][2] = {};
    bf16x8 aL0 = *(const bf16x8*)(ldsA + (c) * 40 + q * 8);
    bf16x8 aL1 = *(const bf16x8*)(ldsA + (16 + c) * 40 + q * 8);
    bf16x8 c0 = *(const bf16x8*)(Cb + h * 1024 + (c) * 32 + q * 8);
    bf16x8 c1 = *(const bf16x8*)(Cb + h * 1024 + (16 + c) * 32 + q * 8);
    acc2[0][0] = MFMA(aL0, c0, acc2[0][0]);
    acc2[0][1] = MFMA(aL0, c1, acc2[0][1]);
    acc2[1][0] = MFMA(aL1, c0, acc2[1][0]);
    acc2[1][1] = MFMA(aL1, c1, acc2[1][1]);
#pragma unroll
    for (int nq = 0; nq < 2; ++nq)
#pragma unroll
        for (int pq = 0; pq < 2; ++pq)
#pragma unroll
            for (int r = 0; r < 4; ++r)
                ldsB[(nq * 16 + q * 4 + r) * 40 + pq * 16 + c] =
                    (bf16)acc2[nq][pq][r];

    {   // coalesced xt/xc stores
        int n = lane >> 1, half = lane & 1;
        bf16x8 t0 = *(const bf16x8*)(ldsA + n * 40 + half * 16);
        bf16x8 t1 = *(const bf16x8*)(ldsA + n * 40 + half * 16 + 8);
        bf16* dst = xt + (bh * NN + n0 + n) * ATN + half * 16;
        *(bf16x8*)(dst) = t0;
        *(bf16x8*)(dst + 8) = t1;
        bf16x8 u0 = *(const bf16x8*)(ldsB + n * 40 + half * 16);
        bf16x8 u1 = *(const bf16x8*)(ldsB + n * 40 + half * 16 + 8);
        bf16* dst2 = xc + (bh * NN + n0 + n) * ATN + half * 16;
        *(bf16x8*)(dst2) = u0;
        *(bf16x8*)(dst2 + 8) = u1;
    }
    {   // xtT via LDS-gathered transpose
        int o = lane >> 1, nh = lane & 1;
        bf16x8 t0, t1;
#pragma unroll
        for (int i = 0; i < 8; ++i) {
            t0[i] = ldsA[(nh * 16 + i) * 40 + o];
            t1[i] = ldsA[(nh * 16 + 8 + i) * 40 + o];
        }
        bf16* dst = xtT + (bh * ATN + o) * NN + n0 + nh * 16;
        *(bf16x8*)(dst) = t0;
        *(bf16x8*)(dst + 8) = t1;
    }
}

// ---------------- kernel B: fused scores/tanh/PV, DMA-pipelined ----------------
// grid 1024 = chunk(4) * b(4) * ntile(64); 512 thr = 8 waves; wave == head.
// EXACT R5 loop body (verified correct, scalar tanh): adj via
// global_load_lds depth 2, 4 LDS buffers, XOR-swizzled source, raw
// s_barrier + vmcnt(6/5/0), mask-0 fences, depth-1 even/odd reg prefetch.
// Each chunk covers 16 m-tiles (512 m).
__global__ __launch_bounds__(512, 4) void k_attn(const float* __restrict__ adj,
                                                 const bf16* __restrict__ xt,
                                                 const bf16* __restrict__ xc,
                                                 const bf16* __restrict__ xtT,
                                                 bf16* __restrict__ sl0,
                                                 bf16* __restrict__ sl1,
                                                 bf16* __restrict__ sl2,
                                                 float* __restrict__ out) {
    __shared__ float adjlds[4 * 1024];      // 4 buffers x 32n x 32m fp32 (16 KB)
    int bid = blockIdx.x;
    int chunk = bid >> 8;                   // 0..3
    int bn = bid & 255;
    int nt = bn & 63, b = bn >> 6;
    int n0 = nt * 32;
    int wave = threadIdx.x >> 6;            // == head
    int lane = threadIdx.x & 63;
    int c = lane & 15, q = lane >> 4;
    int p = 8 * (c >> 2) + (c & 3);         // S A-row permutation
    size_t bh = (size_t)(b * HH + wave);
    const bf16* xt_h = xt + bh * NN * ATN;
    const bf16* xc_h = xc + bh * NN * ATN;
    const bf16* xtT_h = xtT + bh * ATN * NN;
    const float* adj_b = adj + (size_t)b * NN * NN;
    const int m_beg = chunk * 512;          // 16 tiles of 32

    // DMA source (waves 0-3): lane L covers 16B-block Bk = wave*64+L;
    // n = Bk>>3, sub' = Bk&7, global sub = sub' ^ (n&7)  (XOR swizzle)
    int nloc = wave * 8 + (lane >> 3);
    int gsub = (lane & 7) ^ (lane >> 3);
    const float* gA = adj_b + (size_t)(n0 + nloc) * NN + gsub * 4 + m_beg;

#define DMA(t) do { if (wave < 4)                                              \
        GLDS16(gA + (t) * 32, adjlds + ((t) & 3) * 1024 + wave * 256);         \
    } while (0)

    bf16x8 bXC0 = *(const bf16x8*)(xc_h + (n0 + c) * ATN + q * 8);
    bf16x8 bXC1 = *(const bf16x8*)(xc_h + (n0 + 16 + c) * ATN + q * 8);
    f32x4 accO[2][2] = {};                  // O^T [oq][nq]
    const f32x4 z = {0.f, 0.f, 0.f, 0.f};

    // depth-1 register prefetch, explicit even/odd buffers (R5-proven)
    bf16x8 xA0e, xA1e, oA0e, oA1e, xA0o, xA1o, oA0o, oA1o;
#define REGS_E(t) do { int m0 = m_beg + (t) * 32;                              \
        xA0e = *(const bf16x8*)(xt_h + (size_t)(m0 + p) * ATN + q * 8);        \
        xA1e = *(const bf16x8*)(xt_h + (size_t)(m0 + p + 4) * ATN + q * 8);    \
        oA0e = *(const bf16x8*)(xtT_h + (size_t)(c) * NN + m0 + q * 8);        \
        oA1e = *(const bf16x8*)(xtT_h + (size_t)(16 + c) * NN + m0 + q * 8);   \
    } while (0)
#define REGS_O(t) do { int m0 = m_beg + (t) * 32;                              \
        xA0o = *(const bf16x8*)(xt_h + (size_t)(m0 + p) * ATN + q * 8);        \
        xA1o = *(const bf16x8*)(xt_h + (size_t)(m0 + p + 4) * ATN + q * 8);    \
        oA0o = *(const bf16x8*)(xtT_h + (size_t)(c) * NN + m0 + q * 8);        \
        oA1o = *(const bf16x8*)(xtT_h + (size_t)(16 + c) * NN + m0 + q * 8);   \
    } while (0)

    // lane reads adj[n0+c(+16)][m0+8q..8q+7] from swizzled LDS tile
    int ad00 = c * 32 + ((2 * q) ^ (c & 7)) * 4;
    int ad01 = c * 32 + ((2 * q + 1) ^ (c & 7)) * 4;
    int ad10 = (16 + c) * 32 + ((2 * q) ^ (c & 7)) * 4;
    int ad11 = (16 + c) * 32 + ((2 * q + 1) ^ (c & 7)) * 4;

#define COMPUTE(t, xA0, xA1, oA0, oA1) do {                                    \
        const float* lb = adjlds + ((t) & 3) * 1024;                           \
        f32x4 A00 = *(const f32x4*)(lb + ad00);                                \
        f32x4 A01 = *(const f32x4*)(lb + ad01);                                \
        f32x4 A10 = *(const f32x4*)(lb + ad10);                                \
        f32x4 A11 = *(const f32x4*)(lb + ad11);                                \
        f32x4 S0a = MFMA(xA0, bXC0, z);     /* S[m0+8q+r  ][n0+c]    */        \
        f32x4 S0b = MFMA(xA1, bXC0, z);     /* S[m0+8q+4+r][n0+c]    */        \
        f32x4 S1a = MFMA(xA0, bXC1, z);     /* S[m0+8q+r  ][n0+16+c] */        \
        f32x4 S1b = MFMA(xA1, bXC1, z);                                        \
        bf16x8 P0, P1;                                                         \
        _Pragma("unroll") for (int r = 0; r < 4; ++r) {                        \
            P0[r]     = (bf16)fast_tanh(S0a[r] * A00[r]);                      \
            P0[4 + r] = (bf16)fast_tanh(S0b[r] * A01[r]);                      \
            P1[r]     = (bf16)fast_tanh(S1a[r] * A10[r]);                      \
            P1[4 + r] = (bf16)fast_tanh(S1b[r] * A11[r]);                      \
        }                                                                      \
        accO[0][0] = MFMA(oA0, P0, accO[0][0]);                                \
        accO[0][1] = MFMA(oA0, P1, accO[0][1]);                                \
        accO[1][0] = MFMA(oA1, P0, accO[1][0]);                                \
        accO[1][1] = MFMA(oA1, P1, accO[1][1]);                                \
    } while (0)

    // ---- pipeline (R5 pattern, 16 tiles): DMA depth 2, regs depth 1 ----
    REGS_E(0);
    DMA(0);
    DMA(1);
    for (int tt = 0; tt < 14; tt += 2) {
        DMA(tt + 2);
        REGS_O(tt + 1);
        FENCE(); WAITVM6(); BAR(); FENCE();     // younger: DMA(t+1,t+2)+regs(t+1)x4 = 6
        COMPUTE(tt, xA0e, xA1e, oA0e, oA1e);
        DMA(tt + 3);
        REGS_E(tt + 2);
        FENCE(); WAITVM6(); BAR(); FENCE();
        COMPUTE(tt + 1, xA0o, xA1o, oA0o, oA1o);
    }
    // t=14: younger = DMA(15) + regs(15)x4 = 5
    REGS_O(15);
    FENCE(); WAITVM5(); BAR(); FENCE();
    COMPUTE(14, xA0e, xA1e, oA0e, oA1e);
    // t=15: nothing younger
    FENCE(); WAITVM0(); BAR(); FENCE();
    COMPUTE(15, xA0o, xA1o, oA0o, oA1o);

#undef DMA
#undef REGS_E
#undef REGS_O
#undef COMPUTE

    // epilogue: O^T: o = wave*32 + oq*16 + 4q + r, n = n0 + nq*16 + c.
    // chunk 3 -> f32 out (plain store, covers every element once);
    // chunks 0-2 -> bf16 slabs; k_reduce sums.
    if (chunk == 3) {
#pragma unroll
        for (int oq = 0; oq < 2; ++oq)
#pragma unroll
            for (int nq = 0; nq < 2; ++nq) {
                size_t n = n0 + nq * 16 + c;
                *(f32x4*)&out[((size_t)b * NN + n) * 256 + wave * 32 + oq * 16 + 4 * q] =
                    accO[oq][nq];
            }
    } else {
        bf16* sl = (chunk == 0) ? sl0 : (chunk == 1 ? sl1 : sl2);
#pragma unroll
        for (int oq = 0; oq < 2; ++oq)
#pragma unroll
            for (int nq = 0; nq < 2; ++nq) {
                size_t n = n0 + nq * 16 + c;
                bf16x4 v;
#pragma unroll
                for (int r = 0; r < 4; ++r) v[r] = (bf16)accO[oq][nq][r];
                *(bf16x4*)&sl[((size_t)b * NN + n) * 256 + wave * 32 + oq * 16 + 4 * q] = v;
            }
    }
}

// ---------------- kernel C: out += sl0 + sl1 + sl2 ----------------
__global__ __launch_bounds__(256) void k_reduce(const bf16* __restrict__ sl0,
                                                const bf16* __restrict__ sl1,
                                                const bf16* __restrict__ sl2,
                                                float* __restrict__ out) {
    int i = blockIdx.x * 256 + threadIdx.x;   // f32x4 index, 524288 total
    f32x4 a = ((const f32x4*)out)[i];
    bf16x4 s0 = ((const bf16x4*)sl0)[i];
    bf16x4 s1 = ((const bf16x4*)sl1)[i];
    bf16x4 s2 = ((const bf16x4*)sl2)[i];
#pragma unroll
    for (int r = 0; r < 4; ++r)
        a[r] += (float)s0[r] + (float)s1[r] + (float)s2[r];
    ((f32x4*)out)[i] = a;
}

extern "C" void kernel_launch(void* const* d_in, const int* in_sizes, int n_in,
                              void* d_out, int out_size, void* d_ws, size_t ws_size,
                              hipStream_t stream) {
    const float* x    = (const float*)d_in[0];   // [4,2048,256]
    const float* adj  = (const float*)d_in[1];   // [4,2048,2048]
    const float* W    = (const float*)d_in[2];   // [8,256,32]
    const float* bias = (const float*)d_in[3];   // [8,32]
    const float* C    = (const float*)d_in[4];   // [8,32,32]
    float* out = (float*)d_out;                  // [4,2048,256]

    char* ws = (char*)d_ws;                      // 25.3 MB (same as proven R5)
    bf16*  xbf  = (bf16*)(ws + OFF_XBF);         // dead after k_proj -> slab0
    bf16*  xt   = (bf16*)(ws + OFF_XT);
    bf16*  xc   = (bf16*)(ws + OFF_XC);
    bf16*  xtT  = (bf16*)(ws + OFF_XTT);
    bf16*  WT   = (bf16*)(ws + OFF_WT);
    bf16*  Cb   = (bf16*)(ws + OFF_CB);
    bf16*  sl0  = (bf16*)(ws + OFF_XBF);         // reuse
    bf16*  sl1  = (bf16*)(ws + OFF_SLAB);
    bf16*  sl2  = (bf16*)(ws + OFF_SLAB + 4194304u);

    k_prep<<<2336, 256, 0, stream>>>(x, W, C, xbf, WT, Cb);
    k_proj<<<512, 256, 0, stream>>>(xbf, WT, Cb, bias, xt, xc, xtT);
    k_attn<<<1024, 512, 0, stream>>>(adj, xt, xc, xtT, sl0, sl1, sl2, out);
    k_reduce<<<2048, 256, 0, stream>>>(sl0, sl1, sl2, out);
}